// Round 6
// baseline (140.407 us; speedup 1.0000x reference)
//
#include <hip/hip_runtime.h>

// Problem constants (reference: NUM_SAMPLES=8192, EMBED=64, TAU=0.2)
#define EMBED        64
#define NS           8192
#define NTILE        256            // 32-row tiles per matrix
#define JCHUNKS      8
#define JT_PER_CHUNK 32             // NTILE / JCHUNKS
#define C_L2E_TAU    7.21347520444482f   // INV_TAU * log2(e) = 5 / ln(2)

typedef _Float16 half8  __attribute__((ext_vector_type(8)));
typedef float    f32x16 __attribute__((ext_vector_type(16)));

// Raw v_exp_f32: D = 2^x. Input here is in [-2300, +30]: large negatives
// flush to 0 (desired), no NaN/inf path.
static __device__ __forceinline__ float exp2_raw(float x) {
  float r;
  asm("v_exp_f32 %0, %1" : "=v"(r) : "v"(x));
  return r;
}

// ---------------------------------------------------------------------------
// Prep: gather + f32->(h,l) fp16 split + diag, writing fragment-major layout
//   Efrag[mat][tile(256)][frag(8)][lane(64)][8 f16],  frag = hl*4 + ktile
// MFMA 32x32x16 fragment: lane l, elem j -> row = l&31, k = kt*16+(l>>5)*8+j
// Block = one (mat,tile); wave = one ktile; thread reads 32B of its row.
// (unchanged from R5 — proven)
// ---------------------------------------------------------------------------
__global__ __launch_bounds__(256) void prep_kernel(
    const float* __restrict__ users, const float* __restrict__ items,
    const int* __restrict__ uidx, const int* __restrict__ iidx,
    _Float16* __restrict__ Efrag, float* __restrict__ diag) {
  int b = blockIdx.x;
  int mat = b >> 8, tile = b & 255;
  int kt = threadIdx.x >> 6;              // wave index = k-tile
  int lane = threadIdx.x & 63;
  int r = lane & 31;                      // row within tile
  int k0 = kt * 16 + (lane >> 5) * 8;     // my 8-float slice
  int row = tile * 32 + r;
  int src = mat ? iidx[row] : uidx[row];
  const float4* basep =
      (const float4*)((mat ? items : users) + (size_t)src * EMBED + k0);
  float4 v0 = basep[0], v1 = basep[1];
  float vs[8] = {v0.x, v0.y, v0.z, v0.w, v1.x, v1.y, v1.z, v1.w};

  half8 hh, ll;
  float p = 0.f;
  #pragma unroll
  for (int j = 0; j < 8; ++j) {
    float v = vs[j];
    _Float16 h = (_Float16)v;
    hh[j] = h;
    ll[j] = (_Float16)(v - (float)h);
    p = fmaf(v, v, p);
  }
  _Float16* tb = Efrag + (size_t)(mat * NTILE + tile) * 4096;  // 8KB per tile
  *(half8*)(tb + ((kt)     * 64 + lane) * 8) = hh;   // frag kt     (high)
  *(half8*)(tb + ((4 + kt) * 64 + lane) * 8) = ll;   // frag 4+kt   (low)

  // diag = ||row||^2 : lanes l and l^32 hold the two 8-slices of ktile kt
  p += __shfl_xor(p, 32);
  __shared__ float ds[4][32];
  if (lane < 32) ds[kt][lane] = p;
  __syncthreads();
  if (threadIdx.x < 32)
    diag[mat * NS + tile * 32 + threadIdx.x] =
        ds[0][threadIdx.x] + ds[1][threadIdx.x] +
        ds[2][threadIdx.x] + ds[3][threadIdx.x];
}

// ---------------------------------------------------------------------------
// Main v2: NO LDS, NO barriers. Wave = 64-row strip (two 32-row tiles),
// B fragments loaded straight from L1/L2 (Efrag is cache-resident), jt loop
// software-pipelined by 2. Grid: 2 mats x 32 strip-groups x 8 j-chunks = 512
// blocks of 4 independent waves; 2 waves/SIMD resident (launch_bounds cap).
// ---------------------------------------------------------------------------
__global__ __launch_bounds__(256, 2) void ssm_mfma_kernel(
    const _Float16* __restrict__ Efrag, const float* __restrict__ diag,
    float* __restrict__ rowpart) {
  int b = blockIdx.x;
  int jc  = b & (JCHUNKS - 1);
  int sg  = (b >> 3) & 31;
  int mat = b >> 8;
  int wave = threadIdx.x >> 6;
  int lane = threadIdx.x & 63;
  int hf   = lane >> 5;

  int strip = sg * 4 + wave;          // 0..127 : 64-row strip
  int rt0 = strip * 2, rt1 = rt0 + 1; // its two 32-row tiles
  const _Float16* Em = Efrag + (size_t)mat * NTILE * 4096;

  // A fragments for both row-tiles (frags 0..3 = h ktiles, 4..7 = l ktiles)
  half8 a0[8], a1[8];
  #pragma unroll
  for (int f = 0; f < 8; ++f) {
    a0[f] = *(const half8*)(Em + (size_t)rt0 * 4096 + (f * 64 + lane) * 8);
    a1[f] = *(const half8*)(Em + (size_t)rt1 * 4096 + (f * 64 + lane) * 8);
  }

  // negdv = -diag for accumulator init (C slot r -> row (r&3)+8*(r>>2)+4*hf)
  float negdv0[16], negdv1[16];
  #pragma unroll
  for (int r = 0; r < 16; ++r) {
    int rl = (r & 3) + 8 * (r >> 2) + 4 * hf;
    negdv0[r] = -diag[mat * NS + rt0 * 32 + rl];
    negdv1[r] = -diag[mat * NS + rt1 * 32 + rl];
  }

  float rs0[16], rs1[16];
  #pragma unroll
  for (int r = 0; r < 16; ++r) { rs0[r] = 0.f; rs1[r] = 0.f; }

  int tj0 = jc * JT_PER_CHUNK;

  // load B fragments (h+l) of tile tj into 8 half8 regs
  auto loadB = [&](int tj, half8* bb) {
    const _Float16* B = Em + (size_t)tj * 4096;
    #pragma unroll
    for (int f = 0; f < 8; ++f)
      bb[f] = *(const half8*)(B + (f * 64 + lane) * 8);
  };
  // 24 MFMA + two epilogues with one B set
  auto compute = [&](const half8* bb) {
    f32x16 acc;
    #pragma unroll
    for (int r = 0; r < 16; ++r) acc[r] = negdv0[r];
    #pragma unroll
    for (int k = 0; k < 4; ++k)
      acc = __builtin_amdgcn_mfma_f32_32x32x16_f16(a0[k], bb[k], acc, 0, 0, 0);
    #pragma unroll
    for (int k = 0; k < 4; ++k)
      acc = __builtin_amdgcn_mfma_f32_32x32x16_f16(a0[k], bb[4 + k], acc, 0, 0, 0);
    #pragma unroll
    for (int k = 0; k < 4; ++k)
      acc = __builtin_amdgcn_mfma_f32_32x32x16_f16(a0[4 + k], bb[k], acc, 0, 0, 0);
    #pragma unroll
    for (int r = 0; r < 16; ++r)
      rs0[r] += exp2_raw(acc[r] * C_L2E_TAU);

    #pragma unroll
    for (int r = 0; r < 16; ++r) acc[r] = negdv1[r];
    #pragma unroll
    for (int k = 0; k < 4; ++k)
      acc = __builtin_amdgcn_mfma_f32_32x32x16_f16(a1[k], bb[k], acc, 0, 0, 0);
    #pragma unroll
    for (int k = 0; k < 4; ++k)
      acc = __builtin_amdgcn_mfma_f32_32x32x16_f16(a1[k], bb[4 + k], acc, 0, 0, 0);
    #pragma unroll
    for (int k = 0; k < 4; ++k)
      acc = __builtin_amdgcn_mfma_f32_32x32x16_f16(a1[4 + k], bb[k], acc, 0, 0, 0);
    #pragma unroll
    for (int r = 0; r < 16; ++r)
      rs1[r] += exp2_raw(acc[r] * C_L2E_TAU);
  };

  half8 bA[8], bB[8];
  loadB(tj0, bA);
  #pragma unroll 1
  for (int jt = 0; jt < JT_PER_CHUNK; jt += 2) {
    loadB(tj0 + jt + 1, bB);
    compute(bA);
    if (jt + 2 < JT_PER_CHUNK) loadB(tj0 + jt + 2, bA);
    compute(bB);
  }

  // reduce row partials across the 32 lanes of each half, store per chunk
  #pragma unroll
  for (int r = 0; r < 16; ++r) {
    float v0 = rs0[r], v1 = rs1[r];
    #pragma unroll
    for (int off = 16; off; off >>= 1) {
      v0 += __shfl_xor(v0, off);
      v1 += __shfl_xor(v1, off);
    }
    if ((lane & 31) == 0) {
      int rl = (r & 3) + 8 * (r >> 2) + 4 * hf;
      rowpart[jc * (2 * NS) + mat * NS + rt0 * 32 + rl] = v0;
      rowpart[jc * (2 * NS) + mat * NS + rt1 * 32 + rl] = v1;
    }
  }
}

// ---------------------------------------------------------------------------
// Finalize (merged, single block of 1024): per-row chunk-sum, log, means.
// out[0] = loss_u + loss_i, out[1] = loss_u, out[2] = loss_i
// ---------------------------------------------------------------------------
__global__ __launch_bounds__(1024) void finalize_kernel(
    const float* __restrict__ rowpart, float* __restrict__ out) {
  float lu = 0.f, li = 0.f;
  for (int r = threadIdx.x; r < 2 * NS; r += 1024) {
    float s = 0.f;
    #pragma unroll
    for (int c = 0; c < JCHUNKS; ++c) s += rowpart[c * (2 * NS) + r];
    float l = logf(s);
    if (r < NS) lu += l; else li += l;
  }
  #pragma unroll
  for (int off = 32; off; off >>= 1) {
    lu += __shfl_down(lu, off);
    li += __shfl_down(li, off);
  }
  __shared__ float red[2][16];
  int wave = threadIdx.x >> 6;
  if ((threadIdx.x & 63) == 0) { red[0][wave] = lu; red[1][wave] = li; }
  __syncthreads();
  if (threadIdx.x == 0) {
    float su = 0.f, si = 0.f;
    #pragma unroll
    for (int w = 0; w < 16; ++w) { su += red[0][w]; si += red[1][w]; }
    su *= (1.0f / NS);
    si *= (1.0f / NS);
    out[0] = su + si;
    out[1] = su;
    out[2] = si;
  }
}

// ---------------------------------------------------------------------------
// ws: Efrag 4MB | diag 64KB | rowpart 512KB   (identical footprint to R2-R5)
// ---------------------------------------------------------------------------
extern "C" void kernel_launch(void* const* d_in, const int* in_sizes, int n_in,
                              void* d_out, int out_size, void* d_ws, size_t ws_size,
                              hipStream_t stream) {
  const float* users = (const float*)d_in[0];
  const float* items = (const float*)d_in[1];
  const int*   uidx  = (const int*)d_in[2];
  const int*   iidx  = (const int*)d_in[3];
  float* out = (float*)d_out;

  _Float16* Efrag = (_Float16*)d_ws;                         // 2*256*4096 f16 = 4MB
  float* diag     = (float*)((char*)d_ws + (size_t)4194304); // 16384 f32
  float* rowpart  = diag + 2 * NS;                           // 8*16384 f32

  prep_kernel<<<2 * NTILE, 256, 0, stream>>>(users, items, uidx, iidx, Efrag, diag);
  ssm_mfma_kernel<<<2 * 32 * JCHUNKS, 256, 0, stream>>>(Efrag, diag, rowpart);
  finalize_kernel<<<1, 1024, 0, stream>>>(rowpart, out);
}